// Round 3
// baseline (840.180 us; speedup 1.0000x reference)
//
#include <hip/hip_runtime.h>
#include <cmath>

#define BB 2
#define TT 2048
#define NN 16
#define DD 128
#define NROWS (BB*TT*NN)          // 65536 rows of 128
#define PLANE (TT*DD)             // elements per (b,n) plane

typedef unsigned short u16;
typedef unsigned int   u32;

// Static device-global scratch: no dependence on ws_size / d_out layout.
// bf16 Q/K/V in (B,N,T,D) layout; attention output overwrites g_Q.
__device__ u16 g_Q[(size_t)NROWS * DD];
__device__ u16 g_K[(size_t)NROWS * DD];
__device__ u16 g_V[(size_t)NROWS * DD];

__device__ __forceinline__ float bf2f(u16 u) {
    return __uint_as_float(((u32)u) << 16);
}
__device__ __forceinline__ u16 f2bf(float f) {
    u32 b = __float_as_uint(f);
    return (u16)((b + 0x7FFFu + ((b >> 16) & 1u)) >> 16);
}

// ---------------------------------------------------------------------------
// QKV projection: x fp32 rows (b,t,n) -> bf16 Q/K/V rows (b,n,t).
// grid = (NROWS/64, 3); blockIdx.y picks (W,bias,dst).
// LDS 64 KB: WT = transposed 64-k half of W (XOR-swizzled) + 64-row x tile.
// ---------------------------------------------------------------------------
__global__ __launch_bounds__(256)
void qkv_proj_kernel(const float* __restrict__ x,
                     const float* __restrict__ W0, const float* __restrict__ B0,
                     const float* __restrict__ W1, const float* __restrict__ B1,
                     const float* __restrict__ W2, const float* __restrict__ B2)
{
    const int wsel = blockIdx.y;
    const float* W  = (wsel == 0) ? W0 : (wsel == 1) ? W1 : W2;
    const float* Bi = (wsel == 0) ? B0 : (wsel == 1) ? B1 : B2;
    u16*         Ot = (wsel == 0) ? g_Q : (wsel == 1) ? g_K : g_V;

    __shared__ float WT[64*128];   // WT[k][e]: k*128 + ((e4^(k&31))<<2) + el
    __shared__ float xs[64*128];   // plain pitch 128

    const int t  = threadIdx.x;
    const int r0 = blockIdx.x * 64;

    // stage 64 fp32 input rows (contiguous 32 KB)
    {
        const float4* src = (const float4*)(x + (size_t)r0*DD);
        #pragma unroll
        for (int it = 0; it < 8; ++it) {
            int i = t + 256*it;
            ((float4*)xs)[i] = src[i];
        }
    }

    const int te = t & 31;          // e0 = 4*te
    const int tr = t >> 5;          // 8-row group
    const int e0 = te*4;
    const int rb = tr*8;

    float acc[8][4];
    #pragma unroll
    for (int i = 0; i < 8; ++i)
        #pragma unroll
        for (int j = 0; j < 4; ++j) acc[i][j] = 0.f;

    #pragma unroll
    for (int h = 0; h < 2; ++h) {
        const int k0 = h*64;
        if (h) __syncthreads();     // compute done reading WT before restage
        #pragma unroll
        for (int it = 0; it < 8; ++it) {
            int i  = t + 256*it;    // 2048 float4s = 64k half of W
            int e  = i >> 4;        // 0..127
            int kq = i & 15;        // float4 idx within half
            float4 w4 = ((const float4*)W)[e*32 + (k0 >> 2) + kq];
            int e4 = e >> 2, el = e & 3;
            int kl = kq*4;
            WT[(kl+0)*128 + (((e4 ^ ((kl+0)&31)) << 2) + el)] = w4.x;
            WT[(kl+1)*128 + (((e4 ^ ((kl+1)&31)) << 2) + el)] = w4.y;
            WT[(kl+2)*128 + (((e4 ^ ((kl+2)&31)) << 2) + el)] = w4.z;
            WT[(kl+3)*128 + (((e4 ^ ((kl+3)&31)) << 2) + el)] = w4.w;
        }
        __syncthreads();

        for (int kl = 0; kl < 64; kl += 4) {
            float4 x4[8];
            #pragma unroll
            for (int i = 0; i < 8; ++i)
                x4[i] = *(const float4*)&xs[(rb+i)*128 + k0 + kl];
            #pragma unroll
            for (int ik = 0; ik < 4; ++ik) {
                float4 w4 = *(const float4*)&WT[(kl+ik)*128 + ((te ^ ((kl+ik)&31)) << 2)];
                #pragma unroll
                for (int i = 0; i < 8; ++i) {
                    float xv = (&x4[i].x)[ik];
                    acc[i][0] += xv*w4.x; acc[i][1] += xv*w4.y;
                    acc[i][2] += xv*w4.z; acc[i][3] += xv*w4.w;
                }
            }
        }
    }

    float4 bv = *(const float4*)&Bi[e0];
    #pragma unroll
    for (int i = 0; i < 8; ++i) {
        int r = r0 + rb + i;
        int b = r >> 15, rem = r & 32767;      // (b,t,n) -> (b,n,t)
        int tt = rem >> 4, n = rem & 15;
        int orow = (b*NN + n)*TT + tt;
        ushort4 o;
        o.x = f2bf(acc[i][0] + bv.x); o.y = f2bf(acc[i][1] + bv.y);
        o.z = f2bf(acc[i][2] + bv.z); o.w = f2bf(acc[i][3] + bv.w);
        *(ushort4*)&Ot[(size_t)orow*DD + e0] = o;
    }
}

// ---------------------------------------------------------------------------
// Output projection: bf16 att rows (b,n,t) in g_Q -> fp32 out rows (b,t,n).
// ---------------------------------------------------------------------------
__global__ __launch_bounds__(256)
void out_proj_kernel(const float* __restrict__ W, const float* __restrict__ Bi,
                     float* __restrict__ out)
{
    __shared__ float WT[64*128];
    __shared__ float xs[64*128];

    const int t  = threadIdx.x;
    const int r0 = blockIdx.x * 64;

    {
        const u16* src = g_Q + (size_t)r0*DD;
        #pragma unroll
        for (int it = 0; it < 8; ++it) {
            int i = t + 256*it;
            ushort4 u = *(const ushort4*)&src[4*i];
            float4 f;
            f.x = bf2f(u.x); f.y = bf2f(u.y); f.z = bf2f(u.z); f.w = bf2f(u.w);
            ((float4*)xs)[i] = f;
        }
    }

    const int te = t & 31;
    const int tr = t >> 5;
    const int e0 = te*4;
    const int rb = tr*8;

    float acc[8][4];
    #pragma unroll
    for (int i = 0; i < 8; ++i)
        #pragma unroll
        for (int j = 0; j < 4; ++j) acc[i][j] = 0.f;

    #pragma unroll
    for (int h = 0; h < 2; ++h) {
        const int k0 = h*64;
        if (h) __syncthreads();
        #pragma unroll
        for (int it = 0; it < 8; ++it) {
            int i  = t + 256*it;
            int e  = i >> 4;
            int kq = i & 15;
            float4 w4 = ((const float4*)W)[e*32 + (k0 >> 2) + kq];
            int e4 = e >> 2, el = e & 3;
            int kl = kq*4;
            WT[(kl+0)*128 + (((e4 ^ ((kl+0)&31)) << 2) + el)] = w4.x;
            WT[(kl+1)*128 + (((e4 ^ ((kl+1)&31)) << 2) + el)] = w4.y;
            WT[(kl+2)*128 + (((e4 ^ ((kl+2)&31)) << 2) + el)] = w4.z;
            WT[(kl+3)*128 + (((e4 ^ ((kl+3)&31)) << 2) + el)] = w4.w;
        }
        __syncthreads();

        for (int kl = 0; kl < 64; kl += 4) {
            float4 x4[8];
            #pragma unroll
            for (int i = 0; i < 8; ++i)
                x4[i] = *(const float4*)&xs[(rb+i)*128 + k0 + kl];
            #pragma unroll
            for (int ik = 0; ik < 4; ++ik) {
                float4 w4 = *(const float4*)&WT[(kl+ik)*128 + ((te ^ ((kl+ik)&31)) << 2)];
                #pragma unroll
                for (int i = 0; i < 8; ++i) {
                    float xv = (&x4[i].x)[ik];
                    acc[i][0] += xv*w4.x; acc[i][1] += xv*w4.y;
                    acc[i][2] += xv*w4.z; acc[i][3] += xv*w4.w;
                }
            }
        }
    }

    float4 bv = *(const float4*)&Bi[e0];
    #pragma unroll
    for (int i = 0; i < 8; ++i) {
        int r = r0 + rb + i;
        int b = r >> 15, rem = r & 32767;      // (b,n,t) -> (b,t,n)
        int n = rem >> 11, tt = rem & 2047;
        int orow = (b*TT + tt)*NN + n;
        float4 o;
        o.x = acc[i][0] + bv.x; o.y = acc[i][1] + bv.y;
        o.z = acc[i][2] + bv.z; o.w = acc[i][3] + bv.w;
        *(float4*)&out[(size_t)orow*DD + e0] = o;
    }
}

// ---------------------------------------------------------------------------
// Flash attention, fp32 compute, bf16 global tiles. Q-tile 64, K-tile 32.
// LDS 64 KB: Qs 32K (swizzled) + Ks 16K (swizzled, P aliased) + Vs 16K.
// Thread map: cidx=t&15, ridx=t>>4; S: 4 rows x 2 cols; O: 4 rows x 8 d.
// O (bf16) overwrites this block's own g_Q rows.
// ---------------------------------------------------------------------------
__global__ __launch_bounds__(256)
void attn_kernel()
{
    __shared__ float Qs[64*128];    // row*128 + ((f4^(row&31))<<2)
    __shared__ float KsPs[32*128];  // Ks swizzled; Ps pitch 36 aliased
    __shared__ float Vs[32*128];    // plain pitch 128
    float* Ks = KsPs;
    float* Ps = KsPs;

    const int t   = threadIdx.x;
    const int idx = blockIdx.x;
    const int qt  = (TT/64 - 1) - (idx >> 5);   // heaviest q-tiles first
    const int bn  = idx & 31;
    const size_t plane = (size_t)bn * PLANE;
    const u16* Qp = g_Q + plane + (size_t)(qt*64)*DD;
    const u16* Kp = g_K + plane;
    const u16* Vp = g_V + plane;
    u16*       Op = g_Q + plane;

    // stage Q tile (bf16 -> fp32, swizzled)
    #pragma unroll
    for (int it = 0; it < 8; ++it) {
        int i   = t + 256*it;       // 2048 ushort4s
        int row = i >> 5, f4 = i & 31;
        ushort4 u = *(const ushort4*)&Qp[row*DD + 4*f4];
        float4 f;
        f.x = bf2f(u.x); f.y = bf2f(u.y); f.z = bf2f(u.z); f.w = bf2f(u.w);
        *(float4*)&Qs[row*128 + ((f4 ^ (row & 31)) << 2)] = f;
    }

    const int cidx = t & 15;
    const int ridx = t >> 4;
    const int rb   = ridx*4;
    const int d0   = cidx*4;

    float m[4], l[4], acc[4][8];
    #pragma unroll
    for (int i = 0; i < 4; ++i) {
        m[i] = -INFINITY; l[i] = 0.f;
        #pragma unroll
        for (int j = 0; j < 8; ++j) acc[i][j] = 0.f;
    }
    const float scale = 0.08838834764831845f;   // 1/sqrt(128)

    const int nkt = 2*qt + 2;
    for (int kt = 0; kt < nkt; ++kt) {
        __syncthreads();   // prev iter done with Ps(=Ks)/Vs; covers Q-stage on iter 0
        #pragma unroll
        for (int it = 0; it < 4; ++it) {
            int i   = t + 256*it;   // 1024 ushort4s
            int row = i >> 5, f4 = i & 31;
            ushort4 uk = *(const ushort4*)&Kp[(kt*32 + row)*DD + 4*f4];
            ushort4 uv = *(const ushort4*)&Vp[(kt*32 + row)*DD + 4*f4];
            float4 fk, fv;
            fk.x = bf2f(uk.x); fk.y = bf2f(uk.y); fk.z = bf2f(uk.z); fk.w = bf2f(uk.w);
            fv.x = bf2f(uv.x); fv.y = bf2f(uv.y); fv.z = bf2f(uv.z); fv.w = bf2f(uv.w);
            *(float4*)&Ks[row*128 + ((f4 ^ row) << 2)] = fk;
            *(float4*)&Vs[row*128 + 4*f4] = fv;
        }
        __syncthreads();

        // ---- S = Q K^T (4 rows x 2 cols per thread) ----
        float s[4][2];
        #pragma unroll
        for (int i = 0; i < 4; ++i) { s[i][0] = 0.f; s[i][1] = 0.f; }

        for (int kk = 0; kk < 32; ++kk) {
            float4 q4[4], k4[2];
            #pragma unroll
            for (int i = 0; i < 4; ++i) {
                int row = rb + i;
                q4[i] = *(const float4*)&Qs[row*128 + ((kk ^ (row & 31)) << 2)];
            }
            #pragma unroll
            for (int j = 0; j < 2; ++j) {
                int row = cidx + 16*j;
                k4[j] = *(const float4*)&Ks[row*128 + ((kk ^ row) << 2)];
            }
            #pragma unroll
            for (int i = 0; i < 4; ++i)
                #pragma unroll
                for (int j = 0; j < 2; ++j)
                    s[i][j] += q4[i].x*k4[j].x + q4[i].y*k4[j].y
                             + q4[i].z*k4[j].z + q4[i].w*k4[j].w;
        }

        // ---- scale + causal mask (only diagonal tiles kt >= 2*qt) ----
        if (kt >= 2*qt) {
            #pragma unroll
            for (int i = 0; i < 4; ++i) {
                int qg = qt*64 + rb + i;
                #pragma unroll
                for (int j = 0; j < 2; ++j) {
                    int kg = kt*32 + cidx + 16*j;
                    s[i][j] = (kg <= qg) ? s[i][j]*scale : -INFINITY;
                }
            }
        } else {
            #pragma unroll
            for (int i = 0; i < 4; ++i) { s[i][0] *= scale; s[i][1] *= scale; }
        }

        // ---- online softmax over 16 col-lanes ----
        float alpha[4];
        #pragma unroll
        for (int i = 0; i < 4; ++i) {
            float v = fmaxf(s[i][0], s[i][1]);
            #pragma unroll
            for (int off = 1; off < 16; off <<= 1)
                v = fmaxf(v, __shfl_xor(v, off));
            float mn = fmaxf(m[i], v);
            alpha[i] = __expf(m[i] - mn);
            m[i] = mn;
            float p0 = __expf(s[i][0] - mn);
            float p1 = __expf(s[i][1] - mn);
            s[i][0] = p0; s[i][1] = p1;
            float ls = p0 + p1;
            #pragma unroll
            for (int off = 1; off < 16; off <<= 1)
                ls += __shfl_xor(ls, off);
            l[i] = l[i]*alpha[i] + ls;
            #pragma unroll
            for (int j = 0; j < 8; ++j) acc[i][j] *= alpha[i];
        }

        __syncthreads();   // done reading Ks before P overwrites it
        #pragma unroll
        for (int i = 0; i < 4; ++i) {
            Ps[(rb+i)*36 + cidx]      = s[i][0];
            Ps[(rb+i)*36 + cidx + 16] = s[i][1];
        }
        __syncthreads();

        // ---- O += P @ V ----
        for (int ss = 0; ss < 32; ss += 4) {
            float4 p4[4];
            #pragma unroll
            for (int i = 0; i < 4; ++i)
                p4[i] = *(const float4*)&Ps[(rb+i)*36 + ss];
            #pragma unroll
            for (int sj = 0; sj < 4; ++sj) {
                float4 v0 = *(const float4*)&Vs[(ss+sj)*128 + d0];
                float4 v1 = *(const float4*)&Vs[(ss+sj)*128 + 64 + d0];
                #pragma unroll
                for (int i = 0; i < 4; ++i) {
                    float pv = (&p4[i].x)[sj];
                    acc[i][0] += pv*v0.x; acc[i][1] += pv*v0.y;
                    acc[i][2] += pv*v0.z; acc[i][3] += pv*v0.w;
                    acc[i][4] += pv*v1.x; acc[i][5] += pv*v1.y;
                    acc[i][6] += pv*v1.z; acc[i][7] += pv*v1.w;
                }
            }
        }
    }

    // ---- epilogue: normalize, write bf16 O over this block's Q rows ----
    #pragma unroll
    for (int i = 0; i < 4; ++i) {
        float inv = 1.0f / l[i];
        ushort4 o0, o1;
        o0.x = f2bf(acc[i][0]*inv); o0.y = f2bf(acc[i][1]*inv);
        o0.z = f2bf(acc[i][2]*inv); o0.w = f2bf(acc[i][3]*inv);
        o1.x = f2bf(acc[i][4]*inv); o1.y = f2bf(acc[i][5]*inv);
        o1.z = f2bf(acc[i][6]*inv); o1.w = f2bf(acc[i][7]*inv);
        size_t row = (size_t)(qt*64 + rb + i)*DD;
        *(ushort4*)&Op[row + d0]      = o0;
        *(ushort4*)&Op[row + 64 + d0] = o1;
    }
}

extern "C" void kernel_launch(void* const* d_in, const int* in_sizes, int n_in,
                              void* d_out, int out_size, void* d_ws, size_t ws_size,
                              hipStream_t stream)
{
    const float* x  = (const float*)d_in[0];
    const float* wq = (const float*)d_in[1];
    const float* bq = (const float*)d_in[2];
    const float* wk = (const float*)d_in[3];
    const float* bk = (const float*)d_in[4];
    const float* wv = (const float*)d_in[5];
    const float* bv = (const float*)d_in[6];
    const float* wp = (const float*)d_in[7];
    const float* bp = (const float*)d_in[8];
    float* out = (float*)d_out;
    (void)d_ws; (void)ws_size;   // deliberately unused

    dim3 blk(256);
    qkv_proj_kernel<<<dim3(NROWS/64, 3), blk, 0, stream>>>(
        x, wq, bq, wk, bk, wv, bv);
    attn_kernel<<<dim3(BB*NN*(TT/64)), blk, 0, stream>>>();
    out_proj_kernel<<<dim3(NROWS/64, 1), blk, 0, stream>>>(wp, bp, out);
}

// Round 4
// 319.556 us; speedup vs baseline: 2.6292x; 2.6292x over previous
//
#include <hip/hip_runtime.h>
#include <cmath>

#define BB 2
#define TT 2048
#define NN 16
#define DD 128
#define NROWS (BB*TT*NN)          // 65536 rows of 128
#define PLANE (TT*DD)             // elements per (b,n) plane

typedef unsigned short u16;
typedef unsigned int   u32;
typedef __attribute__((ext_vector_type(8)))  short s8v;   // 8 bf16 = 4 VGPRs
typedef __attribute__((ext_vector_type(16))) float vf16;  // MFMA 32x32 acc

// Static device-global scratch (no ws_size assumptions — round-3 lesson).
__device__ u16 g_Q [(size_t)NROWS * DD];   // (b,n,t,d) bf16; overwritten by att
__device__ u16 g_K [(size_t)NROWS * DD];   // (b,n,t,d) bf16
__device__ u16 g_V [(size_t)NROWS * DD];   // (b,n,t,d) bf16
__device__ u16 g_VT[(size_t)NROWS * DD];   // (b,n,d,t) bf16 = V transposed

__device__ __forceinline__ float bf2f(u16 u) {
    return __uint_as_float(((u32)u) << 16);
}
__device__ __forceinline__ u16 f2bf(float f) {
    u32 b = __float_as_uint(f);
    return (u16)((b + 0x7FFFu + ((b >> 16) & 1u)) >> 16);
}

// ---------------------------------------------------------------------------
// QKV projection (unchanged from round 3): x fp32 (b,t,n) -> bf16 (b,n,t).
// ---------------------------------------------------------------------------
__global__ __launch_bounds__(256)
void qkv_proj_kernel(const float* __restrict__ x,
                     const float* __restrict__ W0, const float* __restrict__ B0,
                     const float* __restrict__ W1, const float* __restrict__ B1,
                     const float* __restrict__ W2, const float* __restrict__ B2)
{
    const int wsel = blockIdx.y;
    const float* W  = (wsel == 0) ? W0 : (wsel == 1) ? W1 : W2;
    const float* Bi = (wsel == 0) ? B0 : (wsel == 1) ? B1 : B2;
    u16*         Ot = (wsel == 0) ? g_Q : (wsel == 1) ? g_K : g_V;

    __shared__ float WT[64*128];
    __shared__ float xs[64*128];

    const int t  = threadIdx.x;
    const int r0 = blockIdx.x * 64;

    {
        const float4* src = (const float4*)(x + (size_t)r0*DD);
        #pragma unroll
        for (int it = 0; it < 8; ++it) {
            int i = t + 256*it;
            ((float4*)xs)[i] = src[i];
        }
    }

    const int te = t & 31;
    const int tr = t >> 5;
    const int e0 = te*4;
    const int rb = tr*8;

    float acc[8][4];
    #pragma unroll
    for (int i = 0; i < 8; ++i)
        #pragma unroll
        for (int j = 0; j < 4; ++j) acc[i][j] = 0.f;

    #pragma unroll
    for (int h = 0; h < 2; ++h) {
        const int k0 = h*64;
        if (h) __syncthreads();
        #pragma unroll
        for (int it = 0; it < 8; ++it) {
            int i  = t + 256*it;
            int e  = i >> 4;
            int kq = i & 15;
            float4 w4 = ((const float4*)W)[e*32 + (k0 >> 2) + kq];
            int e4 = e >> 2, el = e & 3;
            int kl = kq*4;
            WT[(kl+0)*128 + (((e4 ^ ((kl+0)&31)) << 2) + el)] = w4.x;
            WT[(kl+1)*128 + (((e4 ^ ((kl+1)&31)) << 2) + el)] = w4.y;
            WT[(kl+2)*128 + (((e4 ^ ((kl+2)&31)) << 2) + el)] = w4.z;
            WT[(kl+3)*128 + (((e4 ^ ((kl+3)&31)) << 2) + el)] = w4.w;
        }
        __syncthreads();

        for (int kl = 0; kl < 64; kl += 4) {
            float4 x4[8];
            #pragma unroll
            for (int i = 0; i < 8; ++i)
                x4[i] = *(const float4*)&xs[(rb+i)*128 + k0 + kl];
            #pragma unroll
            for (int ik = 0; ik < 4; ++ik) {
                float4 w4 = *(const float4*)&WT[(kl+ik)*128 + ((te ^ ((kl+ik)&31)) << 2)];
                #pragma unroll
                for (int i = 0; i < 8; ++i) {
                    float xv = (&x4[i].x)[ik];
                    acc[i][0] += xv*w4.x; acc[i][1] += xv*w4.y;
                    acc[i][2] += xv*w4.z; acc[i][3] += xv*w4.w;
                }
            }
        }
    }

    float4 bv = *(const float4*)&Bi[e0];
    #pragma unroll
    for (int i = 0; i < 8; ++i) {
        int r = r0 + rb + i;
        int b = r >> 15, rem = r & 32767;
        int tt = rem >> 4, n = rem & 15;
        int orow = (b*NN + n)*TT + tt;
        ushort4 o;
        o.x = f2bf(acc[i][0] + bv.x); o.y = f2bf(acc[i][1] + bv.y);
        o.z = f2bf(acc[i][2] + bv.z); o.w = f2bf(acc[i][3] + bv.w);
        *(ushort4*)&Ot[(size_t)orow*DD + e0] = o;
    }
}

// ---------------------------------------------------------------------------
// Output projection (unchanged): bf16 att (b,n,t) in g_Q -> fp32 out (b,t,n).
// ---------------------------------------------------------------------------
__global__ __launch_bounds__(256)
void out_proj_kernel(const float* __restrict__ W, const float* __restrict__ Bi,
                     float* __restrict__ out)
{
    __shared__ float WT[64*128];
    __shared__ float xs[64*128];

    const int t  = threadIdx.x;
    const int r0 = blockIdx.x * 64;

    {
        const u16* src = g_Q + (size_t)r0*DD;
        #pragma unroll
        for (int it = 0; it < 8; ++it) {
            int i = t + 256*it;
            ushort4 u = *(const ushort4*)&src[4*i];
            float4 f;
            f.x = bf2f(u.x); f.y = bf2f(u.y); f.z = bf2f(u.z); f.w = bf2f(u.w);
            ((float4*)xs)[i] = f;
        }
    }

    const int te = t & 31;
    const int tr = t >> 5;
    const int e0 = te*4;
    const int rb = tr*8;

    float acc[8][4];
    #pragma unroll
    for (int i = 0; i < 8; ++i)
        #pragma unroll
        for (int j = 0; j < 4; ++j) acc[i][j] = 0.f;

    #pragma unroll
    for (int h = 0; h < 2; ++h) {
        const int k0 = h*64;
        if (h) __syncthreads();
        #pragma unroll
        for (int it = 0; it < 8; ++it) {
            int i  = t + 256*it;
            int e  = i >> 4;
            int kq = i & 15;
            float4 w4 = ((const float4*)W)[e*32 + (k0 >> 2) + kq];
            int e4 = e >> 2, el = e & 3;
            int kl = kq*4;
            WT[(kl+0)*128 + (((e4 ^ ((kl+0)&31)) << 2) + el)] = w4.x;
            WT[(kl+1)*128 + (((e4 ^ ((kl+1)&31)) << 2) + el)] = w4.y;
            WT[(kl+2)*128 + (((e4 ^ ((kl+2)&31)) << 2) + el)] = w4.z;
            WT[(kl+3)*128 + (((e4 ^ ((kl+3)&31)) << 2) + el)] = w4.w;
        }
        __syncthreads();

        for (int kl = 0; kl < 64; kl += 4) {
            float4 x4[8];
            #pragma unroll
            for (int i = 0; i < 8; ++i)
                x4[i] = *(const float4*)&xs[(rb+i)*128 + k0 + kl];
            #pragma unroll
            for (int ik = 0; ik < 4; ++ik) {
                float4 w4 = *(const float4*)&WT[(kl+ik)*128 + ((te ^ ((kl+ik)&31)) << 2)];
                #pragma unroll
                for (int i = 0; i < 8; ++i) {
                    float xv = (&x4[i].x)[ik];
                    acc[i][0] += xv*w4.x; acc[i][1] += xv*w4.y;
                    acc[i][2] += xv*w4.z; acc[i][3] += xv*w4.w;
                }
            }
        }
    }

    float4 bv = *(const float4*)&Bi[e0];
    #pragma unroll
    for (int i = 0; i < 8; ++i) {
        int r = r0 + rb + i;
        int b = r >> 15, rem = r & 32767;
        int n = rem >> 11, tt = rem & 2047;
        int orow = (b*TT + tt)*NN + n;
        float4 o;
        o.x = acc[i][0] + bv.x; o.y = acc[i][1] + bv.y;
        o.z = acc[i][2] + bv.z; o.w = acc[i][3] + bv.w;
        *(float4*)&out[(size_t)orow*DD + e0] = o;
    }
}

// ---------------------------------------------------------------------------
// V transpose: g_V (b,n,t,d) -> g_VT (b,n,d,t). Reads coalesced per-instruction
// (64 lanes x consecutive d), writes ushort8 rows.
// grid = 32 planes x 128 segs; block 256 = 4 waves x (64 d, 8 t).
// ---------------------------------------------------------------------------
__global__ __launch_bounds__(256)
void vtrans_kernel()
{
    const int t   = threadIdx.x;
    const int blk = blockIdx.x;
    const int pl  = blk >> 7;
    const int seg = blk & 127;
    const size_t plane = (size_t)pl * PLANE;
    const int w = t >> 6, lane = t & 63;
    const int d   = (w & 1)*64 + lane;
    const int tt0 = seg*16 + (w >> 1)*8;

    const u16* src = g_V + plane + (size_t)tt0*DD + d;
    u16 e[8];
    #pragma unroll
    for (int i = 0; i < 8; ++i) e[i] = src[(size_t)i*DD];
    uint4 pk;
    pk.x = (u32)e[0] | ((u32)e[1] << 16);
    pk.y = (u32)e[2] | ((u32)e[3] << 16);
    pk.z = (u32)e[4] | ((u32)e[5] << 16);
    pk.w = (u32)e[6] | ((u32)e[7] << 16);
    *(uint4*)&g_VT[plane + (size_t)d*TT + tt0] = pk;
}

// ---------------------------------------------------------------------------
// MFMA flash attention. Block = (bn, q-tile of 128) = 4 waves x 32-q bands.
// K-tile 64. S^T = K·Q^T via mfma_f32_32x32x16_bf16 (C: lane holds 16 keys of
// ONE q-col -> scalar m/l per lane + shfl_xor(32)). P stays in registers as
// the PV A-operand (C-layout == A-layout under k-permutation pi; V-fragments
// load with the same pi from transposed V tile). O overwrites own g_Q rows.
// LDS 35.8 KB: Ks 64x136 u16, Vt 128x72 u16 (pitches => uniform banking).
// ---------------------------------------------------------------------------
__global__ __launch_bounds__(256, 2)
void attn_kernel()
{
    __shared__ u16 Ks[64*136];
    __shared__ u16 Vt[128*72];

    const int t   = threadIdx.x;
    const int grp = blockIdx.x >> 5;              // 0..15
    const int bn  = blockIdx.x & 31;
    const int qt  = (grp < 8) ? (15 - grp) : (grp - 8);  // balanced pairs: 15-g | g
    const int q0  = qt * 128;
    const size_t plane = (size_t)bn * PLANE;

    const int w      = t >> 6;
    const int lane   = t & 63;
    const int lane31 = lane & 31;
    const int q2     = lane >> 5;
    const int qband  = q0 + 32*w;
    const int qrow   = qband + lane31;

    // ---- Q fragments: whole 32-q band held in registers for the kernel ----
    s8v qf[8];
    {
        const u16* Qg = g_Q + plane + (size_t)qrow * DD;
        #pragma unroll
        for (int s = 0; s < 8; ++s)
            qf[s] = *(const s8v*)&Qg[s*16 + q2*8];
    }

    vf16 accO[4];
    #pragma unroll
    for (int dt = 0; dt < 4; ++dt)
        #pragma unroll
        for (int i = 0; i < 16; ++i) accO[dt][i] = 0.f;

    float mrow = -INFINITY, lrow = 0.f;
    const float scale = 0.08838834764831845f;     // 1/sqrt(128)

    const int nkt = 2*qt + 2;
    for (int kt = 0; kt < nkt; ++kt) {
        const int k0 = kt*64;
        __syncthreads();                          // prev iter done with Ks/Vt
        {
            const u16* Kg = g_K  + plane + (size_t)k0*DD;
            const u16* Vg = g_VT + plane + k0;
            #pragma unroll
            for (int c = 0; c < 4; ++c) {
                int j  = t + 256*c;
                int kr = j >> 4, kc = j & 15;     // K: 64 rows x 16 chunks
                *(uint4*)&Ks[kr*136 + kc*8] = *(const uint4*)&Kg[kr*128 + kc*8];
                int vr = j >> 3, vc = j & 7;      // VT: 128 rows x 8 chunks
                *(uint4*)&Vt[vr*72 + vc*8] = *(const uint4*)&Vg[(size_t)vr*TT + vc*8];
            }
        }
        __syncthreads();

        if (k0 > qband + 31) continue;            // fully-masked for this wave

        // ---- S^T = K · Q^T : 2 key-subtiles x 8 k-steps ----
        vf16 accS[2];
        #pragma unroll
        for (int kk = 0; kk < 2; ++kk)
            #pragma unroll
            for (int i = 0; i < 16; ++i) accS[kk][i] = 0.f;
        #pragma unroll
        for (int s = 0; s < 8; ++s) {
            #pragma unroll
            for (int kk = 0; kk < 2; ++kk) {
                s8v a = *(const s8v*)&Ks[(kk*32 + lane31)*136 + s*16 + q2*8];
                accS[kk] = __builtin_amdgcn_mfma_f32_32x32x16_bf16(a, qf[s], accS[kk], 0, 0, 0);
            }
        }

        // ---- scale + causal mask ----
        float p[2][16];
        const bool tail = (k0 + 63 > qband);
        #pragma unroll
        for (int kk = 0; kk < 2; ++kk)
            #pragma unroll
            for (int r = 0; r < 16; ++r) {
                float sv = accS[kk][r] * scale;
                if (tail) {
                    int keyg = k0 + kk*32 + (r & 3) + 8*(r >> 2) + 4*q2;
                    if (keyg > qrow) sv = -INFINITY;
                }
                p[kk][r] = sv;
            }

        // ---- online softmax: scalar m/l per lane (one q-col each) ----
        float vmax = -INFINITY;
        #pragma unroll
        for (int kk = 0; kk < 2; ++kk)
            #pragma unroll
            for (int r = 0; r < 16; ++r) vmax = fmaxf(vmax, p[kk][r]);
        vmax = fmaxf(vmax, __shfl_xor(vmax, 32));
        float mold = mrow;
        float mnew = fmaxf(mold, vmax);
        float alpha = __expf(mold - mnew);
        mrow = mnew;
        float ls = 0.f;
        #pragma unroll
        for (int kk = 0; kk < 2; ++kk)
            #pragma unroll
            for (int r = 0; r < 16; ++r) {
                float e = __expf(p[kk][r] - mnew);
                p[kk][r] = e;
                ls += e;
            }
        ls += __shfl_xor(ls, 32);
        lrow = lrow*alpha + ls;

        if (__any(mnew > mold)) {                 // O-rescale only when m moved
            float ar[16];
            #pragma unroll
            for (int r = 0; r < 16; ++r)
                ar[r] = __shfl(alpha, (r & 3) + 8*(r >> 2) + 4*q2);
            #pragma unroll
            for (int dt = 0; dt < 4; ++dt)
                #pragma unroll
                for (int r = 0; r < 16; ++r) accO[dt][r] *= ar[r];
        }

        // ---- pack P (bf16, trunc) as PV A-fragments ----
        s8v pf[4];
        #pragma unroll
        for (int tau = 0; tau < 4; ++tau) {
            int kk = tau >> 1, rb = (tau & 1)*8;
            s8v v;
            #pragma unroll
            for (int j = 0; j < 8; ++j)
                v[j] = (short)(__float_as_uint(p[kk][rb + j]) >> 16);
            pf[tau] = v;
        }

        // ---- O += P · V (V-frags permuted to match P's C-layout) ----
        #pragma unroll
        for (int dt = 0; dt < 4; ++dt) {
            const u16* vp = &Vt[(dt*32 + lane31)*72];
            #pragma unroll
            for (int tau = 0; tau < 4; ++tau) {
                const u16* q = vp + 16*tau + 4*q2;
                short4 lo = *(const short4*)q;
                short4 hi = *(const short4*)(q + 8);
                s8v bvv = {lo.x, lo.y, lo.z, lo.w, hi.x, hi.y, hi.z, hi.w};
                accO[dt] = __builtin_amdgcn_mfma_f32_32x32x16_bf16(pf[tau], bvv, accO[dt], 0, 0, 0);
            }
        }
    }

    // ---- epilogue: normalize, write bf16 O over own g_Q rows ----
    float inv = 1.0f / lrow;
    #pragma unroll
    for (int r = 0; r < 16; ++r) {
        int rl = (r & 3) + 8*(r >> 2) + 4*q2;
        float ir = __shfl(inv, rl);
        u16* op = g_Q + plane + (size_t)(qband + rl)*DD;
        #pragma unroll
        for (int dt = 0; dt < 4; ++dt)
            op[dt*32 + lane31] = f2bf(accO[dt][r] * ir);
    }
}

extern "C" void kernel_launch(void* const* d_in, const int* in_sizes, int n_in,
                              void* d_out, int out_size, void* d_ws, size_t ws_size,
                              hipStream_t stream)
{
    const float* x  = (const float*)d_in[0];
    const float* wq = (const float*)d_in[1];
    const float* bq = (const float*)d_in[2];
    const float* wk = (const float*)d_in[3];
    const float* bk = (const float*)d_in[4];
    const float* wv = (const float*)d_in[5];
    const float* bv = (const float*)d_in[6];
    const float* wp = (const float*)d_in[7];
    const float* bp = (const float*)d_in[8];
    float* out = (float*)d_out;
    (void)d_ws; (void)ws_size;

    dim3 blk(256);
    qkv_proj_kernel<<<dim3(NROWS/64, 3), blk, 0, stream>>>(
        x, wq, bq, wk, bk, wv, bv);
    vtrans_kernel<<<dim3(BB*NN*128), blk, 0, stream>>>();
    attn_kernel<<<dim3(BB*NN*(TT/128)), blk, 0, stream>>>();
    out_proj_kernel<<<dim3(NROWS/64, 1), blk, 0, stream>>>(wp, bp, out);
}

// Round 5
// 231.430 us; speedup vs baseline: 3.6304x; 1.3808x over previous
//
#include <hip/hip_runtime.h>
#include <cmath>

#define BB 2
#define TT 2048
#define NN 16
#define DD 128
#define NROWS (BB*TT*NN)          // 65536 rows of 128
#define PLANE (TT*DD)             // elements per (b,n) plane

typedef unsigned short u16;
typedef unsigned int   u32;
typedef __attribute__((ext_vector_type(8)))  short s8v;   // 8 bf16 = 4 VGPRs
typedef __attribute__((ext_vector_type(16))) float vf16;  // MFMA 32x32 acc

// Static device-global scratch (no ws_size assumptions — round-3 lesson).
__device__ u16 g_Q [(size_t)NROWS * DD];   // (b,n,t,d) bf16; overwritten by att
__device__ u16 g_K [(size_t)NROWS * DD];   // (b,n,t,d) bf16
__device__ u16 g_V [(size_t)NROWS * DD];   // (b,n,t,d) bf16
__device__ u16 g_VT[(size_t)NROWS * DD];   // (b,n,d,t) bf16 = V transposed

__device__ __forceinline__ float bf2f(u16 u) {
    return __uint_as_float(((u32)u) << 16);
}
__device__ __forceinline__ u16 f2bf(float f) {
    u32 b = __float_as_uint(f);
    return (u16)((b + 0x7FFFu + ((b >> 16) & 1u)) >> 16);
}
__device__ __forceinline__ uint4 pack8(const float4& a, const float4& b) {
    uint4 p;
    p.x = (u32)f2bf(a.x) | ((u32)f2bf(a.y) << 16);
    p.y = (u32)f2bf(a.z) | ((u32)f2bf(a.w) << 16);
    p.z = (u32)f2bf(b.x) | ((u32)f2bf(b.y) << 16);
    p.w = (u32)f2bf(b.z) | ((u32)f2bf(b.w) << 16);
    return p;
}

// ---------------------------------------------------------------------------
// MFMA QKV projection: x fp32 rows (b,t,n) -> bf16 Q/K/V rows (b,n,t).
// out = X · W^T: A-frag = X row (k contig), B-frag = W row e (k contig),
// C: col(lane&31)=e, 16 rows in regs. Block = 128 rows; grid.y picks Q/K/V.
// LDS 68 KB: Ws + Xs bf16, pitch 136 u16 (dword pitch 68 == conflict-free).
// ---------------------------------------------------------------------------
__global__ __launch_bounds__(256)
void qkv_proj_kernel(const float* __restrict__ x,
                     const float* __restrict__ W0, const float* __restrict__ B0,
                     const float* __restrict__ W1, const float* __restrict__ B1,
                     const float* __restrict__ W2, const float* __restrict__ B2)
{
    const int wsel = blockIdx.y;
    const float* W  = (wsel == 0) ? W0 : (wsel == 1) ? W1 : W2;
    const float* Bi = (wsel == 0) ? B0 : (wsel == 1) ? B1 : B2;
    u16*         Ot = (wsel == 0) ? g_Q : (wsel == 1) ? g_K : g_V;

    __shared__ u16 Ws[128*136];
    __shared__ u16 Xs[128*136];

    const int t  = threadIdx.x;
    const int r0 = blockIdx.x * 128;
    const float4* xsrc = (const float4*)(x + (size_t)r0*DD);

    // stage W and X tiles as bf16 (8 elems per (thread,iter); coalesced loads)
    #pragma unroll
    for (int it = 0; it < 8; ++it) {
        int i  = t + 256*it;        // 2048 chunks of 8 elems
        int e  = i >> 4;            // row 0..127
        int c8 = i & 15;            // 8-elem chunk
        float4 wa = ((const float4*)W)[2*i];
        float4 wb = ((const float4*)W)[2*i + 1];
        *(uint4*)&Ws[e*136 + c8*8] = pack8(wa, wb);
        float4 xa = xsrc[2*i];
        float4 xb = xsrc[2*i + 1];
        *(uint4*)&Xs[e*136 + c8*8] = pack8(xa, xb);
    }
    __syncthreads();

    const int w   = t >> 6;
    const int l31 = t & 31;
    const int q2  = (t >> 5) & 1;

    // A-fragments: this wave's 32-row band, held in registers
    s8v af[8];
    #pragma unroll
    for (int s = 0; s < 8; ++s)
        af[s] = *(const s8v*)&Xs[(w*32 + l31)*136 + s*16 + q2*8];

    vf16 acc[4];
    #pragma unroll
    for (int et = 0; et < 4; ++et)
        #pragma unroll
        for (int i = 0; i < 16; ++i) acc[et][i] = 0.f;

    #pragma unroll
    for (int s = 0; s < 8; ++s) {
        #pragma unroll
        for (int et = 0; et < 4; ++et) {
            s8v bf = *(const s8v*)&Ws[(et*32 + l31)*136 + s*16 + q2*8];
            acc[et] = __builtin_amdgcn_mfma_f32_32x32x16_bf16(af[s], bf, acc[et], 0, 0, 0);
        }
    }

    float bb[4];
    #pragma unroll
    for (int et = 0; et < 4; ++et) bb[et] = Bi[et*32 + l31];

    #pragma unroll
    for (int r = 0; r < 16; ++r) {
        int rl = (r & 3) + 8*(r >> 2) + 4*q2;
        int rg = r0 + w*32 + rl;
        int b = rg >> 15, rem = rg & 32767;   // (b,t,n) -> (b,n,t)
        int tt = rem >> 4, n = rem & 15;
        size_t orow = (size_t)((b*NN + n)*TT + tt) * DD;
        #pragma unroll
        for (int et = 0; et < 4; ++et)
            Ot[orow + et*32 + l31] = f2bf(acc[et][r] + bb[et]);
    }
}

// ---------------------------------------------------------------------------
// MFMA output projection: bf16 att rows (b,n,t) in g_Q -> fp32 out (b,t,n).
// A-frags straight from global (one b128 per frag); W staged bf16 in LDS.
// ---------------------------------------------------------------------------
__global__ __launch_bounds__(256)
void out_proj_kernel(const float* __restrict__ W, const float* __restrict__ Bi,
                     float* __restrict__ out)
{
    __shared__ u16 Ws[128*136];

    const int t  = threadIdx.x;
    const int r0 = blockIdx.x * 128;

    #pragma unroll
    for (int it = 0; it < 8; ++it) {
        int i  = t + 256*it;
        int e  = i >> 4;
        int c8 = i & 15;
        float4 wa = ((const float4*)W)[2*i];
        float4 wb = ((const float4*)W)[2*i + 1];
        *(uint4*)&Ws[e*136 + c8*8] = pack8(wa, wb);
    }

    const int w   = t >> 6;
    const int l31 = t & 31;
    const int q2  = (t >> 5) & 1;

    s8v af[8];
    {
        const u16* src = g_Q + (size_t)(r0 + w*32 + l31)*DD;
        #pragma unroll
        for (int s = 0; s < 8; ++s)
            af[s] = *(const s8v*)&src[s*16 + q2*8];
    }
    __syncthreads();

    vf16 acc[4];
    #pragma unroll
    for (int et = 0; et < 4; ++et)
        #pragma unroll
        for (int i = 0; i < 16; ++i) acc[et][i] = 0.f;

    #pragma unroll
    for (int s = 0; s < 8; ++s) {
        #pragma unroll
        for (int et = 0; et < 4; ++et) {
            s8v bf = *(const s8v*)&Ws[(et*32 + l31)*136 + s*16 + q2*8];
            acc[et] = __builtin_amdgcn_mfma_f32_32x32x16_bf16(af[s], bf, acc[et], 0, 0, 0);
        }
    }

    float bb[4];
    #pragma unroll
    for (int et = 0; et < 4; ++et) bb[et] = Bi[et*32 + l31];

    #pragma unroll
    for (int r = 0; r < 16; ++r) {
        int rl = (r & 3) + 8*(r >> 2) + 4*q2;
        int rg = r0 + w*32 + rl;
        int b = rg >> 15, rem = rg & 32767;   // (b,n,t) -> (b,t,n)
        int n = rem >> 11, tt = rem & 2047;
        size_t orow = (size_t)((b*TT + tt)*NN + n) * DD;
        #pragma unroll
        for (int et = 0; et < 4; ++et)
            out[orow + et*32 + l31] = acc[et][r] + bb[et];
    }
}

// ---------------------------------------------------------------------------
// V transpose (unchanged): g_V (b,n,t,d) -> g_VT (b,n,d,t).
// ---------------------------------------------------------------------------
__global__ __launch_bounds__(256)
void vtrans_kernel()
{
    const int t   = threadIdx.x;
    const int blk = blockIdx.x;
    const int pl  = blk >> 7;
    const int seg = blk & 127;
    const size_t plane = (size_t)pl * PLANE;
    const int w = t >> 6, lane = t & 63;
    const int d   = (w & 1)*64 + lane;
    const int tt0 = seg*16 + (w >> 1)*8;

    const u16* src = g_V + plane + (size_t)tt0*DD + d;
    u16 e[8];
    #pragma unroll
    for (int i = 0; i < 8; ++i) e[i] = src[(size_t)i*DD];
    uint4 pk;
    pk.x = (u32)e[0] | ((u32)e[1] << 16);
    pk.y = (u32)e[2] | ((u32)e[3] << 16);
    pk.z = (u32)e[4] | ((u32)e[5] << 16);
    pk.w = (u32)e[6] | ((u32)e[7] << 16);
    *(uint4*)&g_VT[plane + (size_t)d*TT + tt0] = pk;
}

// ---------------------------------------------------------------------------
// MFMA flash attention (unchanged from round 4).
// ---------------------------------------------------------------------------
__global__ __launch_bounds__(256, 2)
void attn_kernel()
{
    __shared__ u16 Ks[64*136];
    __shared__ u16 Vt[128*72];

    const int t   = threadIdx.x;
    const int grp = blockIdx.x >> 5;              // 0..15
    const int bn  = blockIdx.x & 31;
    const int qt  = (grp < 8) ? (15 - grp) : (grp - 8);  // balanced pairs
    const int q0  = qt * 128;
    const size_t plane = (size_t)bn * PLANE;

    const int w      = t >> 6;
    const int lane   = t & 63;
    const int lane31 = lane & 31;
    const int q2     = lane >> 5;
    const int qband  = q0 + 32*w;
    const int qrow   = qband + lane31;

    s8v qf[8];
    {
        const u16* Qg = g_Q + plane + (size_t)qrow * DD;
        #pragma unroll
        for (int s = 0; s < 8; ++s)
            qf[s] = *(const s8v*)&Qg[s*16 + q2*8];
    }

    vf16 accO[4];
    #pragma unroll
    for (int dt = 0; dt < 4; ++dt)
        #pragma unroll
        for (int i = 0; i < 16; ++i) accO[dt][i] = 0.f;

    float mrow = -INFINITY, lrow = 0.f;
    const float scale = 0.08838834764831845f;     // 1/sqrt(128)

    const int nkt = 2*qt + 2;
    for (int kt = 0; kt < nkt; ++kt) {
        const int k0 = kt*64;
        __syncthreads();
        {
            const u16* Kg = g_K  + plane + (size_t)k0*DD;
            const u16* Vg = g_VT + plane + k0;
            #pragma unroll
            for (int c = 0; c < 4; ++c) {
                int j  = t + 256*c;
                int kr = j >> 4, kc = j & 15;
                *(uint4*)&Ks[kr*136 + kc*8] = *(const uint4*)&Kg[kr*128 + kc*8];
                int vr = j >> 3, vc = j & 7;
                *(uint4*)&Vt[vr*72 + vc*8] = *(const uint4*)&Vg[(size_t)vr*TT + vc*8];
            }
        }
        __syncthreads();

        if (k0 > qband + 31) continue;

        vf16 accS[2];
        #pragma unroll
        for (int kk = 0; kk < 2; ++kk)
            #pragma unroll
            for (int i = 0; i < 16; ++i) accS[kk][i] = 0.f;
        #pragma unroll
        for (int s = 0; s < 8; ++s) {
            #pragma unroll
            for (int kk = 0; kk < 2; ++kk) {
                s8v a = *(const s8v*)&Ks[(kk*32 + lane31)*136 + s*16 + q2*8];
                accS[kk] = __builtin_amdgcn_mfma_f32_32x32x16_bf16(a, qf[s], accS[kk], 0, 0, 0);
            }
        }

        float p[2][16];
        const bool tail = (k0 + 63 > qband);
        #pragma unroll
        for (int kk = 0; kk < 2; ++kk)
            #pragma unroll
            for (int r = 0; r < 16; ++r) {
                float sv = accS[kk][r] * scale;
                if (tail) {
                    int keyg = k0 + kk*32 + (r & 3) + 8*(r >> 2) + 4*q2;
                    if (keyg > qrow) sv = -INFINITY;
                }
                p[kk][r] = sv;
            }

        float vmax = -INFINITY;
        #pragma unroll
        for (int kk = 0; kk < 2; ++kk)
            #pragma unroll
            for (int r = 0; r < 16; ++r) vmax = fmaxf(vmax, p[kk][r]);
        vmax = fmaxf(vmax, __shfl_xor(vmax, 32));
        float mold = mrow;
        float mnew = fmaxf(mold, vmax);
        float alpha = __expf(mold - mnew);
        mrow = mnew;
        float ls = 0.f;
        #pragma unroll
        for (int kk = 0; kk < 2; ++kk)
            #pragma unroll
            for (int r = 0; r < 16; ++r) {
                float e = __expf(p[kk][r] - mnew);
                p[kk][r] = e;
                ls += e;
            }
        ls += __shfl_xor(ls, 32);
        lrow = lrow*alpha + ls;

        if (__any(mnew > mold)) {
            float ar[16];
            #pragma unroll
            for (int r = 0; r < 16; ++r)
                ar[r] = __shfl(alpha, (r & 3) + 8*(r >> 2) + 4*q2);
            #pragma unroll
            for (int dt = 0; dt < 4; ++dt)
                #pragma unroll
                for (int r = 0; r < 16; ++r) accO[dt][r] *= ar[r];
        }

        s8v pf[4];
        #pragma unroll
        for (int tau = 0; tau < 4; ++tau) {
            int kk = tau >> 1, rb = (tau & 1)*8;
            s8v v;
            #pragma unroll
            for (int j = 0; j < 8; ++j)
                v[j] = (short)(__float_as_uint(p[kk][rb + j]) >> 16);
            pf[tau] = v;
        }

        #pragma unroll
        for (int dt = 0; dt < 4; ++dt) {
            const u16* vp = &Vt[(dt*32 + lane31)*72];
            #pragma unroll
            for (int tau = 0; tau < 4; ++tau) {
                const u16* q = vp + 16*tau + 4*q2;
                short4 lo = *(const short4*)q;
                short4 hi = *(const short4*)(q + 8);
                s8v bvv = {lo.x, lo.y, lo.z, lo.w, hi.x, hi.y, hi.z, hi.w};
                accO[dt] = __builtin_amdgcn_mfma_f32_32x32x16_bf16(pf[tau], bvv, accO[dt], 0, 0, 0);
            }
        }
    }

    float inv = 1.0f / lrow;
    #pragma unroll
    for (int r = 0; r < 16; ++r) {
        int rl = (r & 3) + 8*(r >> 2) + 4*q2;
        float ir = __shfl(inv, rl);
        u16* op = g_Q + plane + (size_t)(qband + rl)*DD;
        #pragma unroll
        for (int dt = 0; dt < 4; ++dt)
            op[dt*32 + lane31] = f2bf(accO[dt][r] * ir);
    }
}

extern "C" void kernel_launch(void* const* d_in, const int* in_sizes, int n_in,
                              void* d_out, int out_size, void* d_ws, size_t ws_size,
                              hipStream_t stream)
{
    const float* x  = (const float*)d_in[0];
    const float* wq = (const float*)d_in[1];
    const float* bq = (const float*)d_in[2];
    const float* wk = (const float*)d_in[3];
    const float* bk = (const float*)d_in[4];
    const float* wv = (const float*)d_in[5];
    const float* bv = (const float*)d_in[6];
    const float* wp = (const float*)d_in[7];
    const float* bp = (const float*)d_in[8];
    float* out = (float*)d_out;
    (void)d_ws; (void)ws_size;

    dim3 blk(256);
    qkv_proj_kernel<<<dim3(NROWS/128, 3), blk, 0, stream>>>(
        x, wq, bq, wk, bk, wv, bv);
    vtrans_kernel<<<dim3(BB*NN*128), blk, 0, stream>>>();
    attn_kernel<<<dim3(BB*NN*(TT/128)), blk, 0, stream>>>();
    out_proj_kernel<<<dim3(NROWS/128, 1), blk, 0, stream>>>(wp, bp, out);
}

// Round 6
// 207.987 us; speedup vs baseline: 4.0396x; 1.1127x over previous
//
#include <hip/hip_runtime.h>
#include <cmath>

#define BB 2
#define TT 2048
#define NN 16
#define DD 128
#define NROWS (BB*TT*NN)          // 65536 rows of 128
#define PLANE (TT*DD)             // elements per (b,n) plane
#define KP 132                    // Ks/Xs/Ws pitch (u16): 66 dw == 2 mod 32
#define VP 68                     // Vt pitch (u16): 34 dw == 2 mod 32

typedef unsigned short u16;
typedef unsigned int   u32;
typedef __attribute__((ext_vector_type(8)))  short s8v;   // 8 bf16 = 4 VGPRs
typedef __attribute__((ext_vector_type(16))) float vf16;  // MFMA 32x32 acc

// Static device-global scratch (no ws_size assumptions — round-3 lesson).
__device__ u16 g_Q [(size_t)NROWS * DD];   // (b,n,t,d) bf16; overwritten by att
__device__ u16 g_K [(size_t)NROWS * DD];   // (b,n,t,d) bf16
__device__ u16 g_V [(size_t)NROWS * DD];   // (b,n,t,d) bf16
__device__ u16 g_VT[(size_t)NROWS * DD];   // (b,n,d,t) bf16 = V transposed

__device__ __forceinline__ u16 f2bf(float f) {          // round-half-up, 2 ops
    return (u16)((__float_as_uint(f) + 0x8000u) >> 16);
}
__device__ __forceinline__ u32 pk2(float a, float b) {  // pack 2 bf16
    return ((__float_as_uint(a) + 0x8000u) >> 16)
         | ((__float_as_uint(b) + 0x8000u) & 0xFFFF0000u);
}
__device__ __forceinline__ void st8(u16* p, const float4& a, const float4& b) {
    uint2 lo, hi;
    lo.x = pk2(a.x, a.y); lo.y = pk2(a.z, a.w);
    hi.x = pk2(b.x, b.y); hi.y = pk2(b.z, b.w);
    *(uint2*)p       = lo;
    *(uint2*)(p + 4) = hi;
}
__device__ __forceinline__ s8v ld8(const u16* p) {      // two aligned b64 reads
    short4 a = *(const short4*)p;
    short4 b = *(const short4*)(p + 4);
    return (s8v){a.x, a.y, a.z, a.w, b.x, b.y, b.z, b.w};
}

// ---------------------------------------------------------------------------
// Fused QKV projection: x fp32 rows (b,t,n) -> bf16 Q/K/V rows (b,n,t).
// X staged once (bf16), A-frags in registers; 3 weight tiles staged in turn.
// All LDS frag access = aligned b64 at pitch 132 (2-way banking = free).
// ---------------------------------------------------------------------------
__global__ __launch_bounds__(256)
void qkv_proj_kernel(const float* __restrict__ x,
                     const float* __restrict__ Wq, const float* __restrict__ Bq,
                     const float* __restrict__ Wk, const float* __restrict__ Bk,
                     const float* __restrict__ Wv, const float* __restrict__ Bv)
{
    __shared__ u16 Xs[128*KP];
    __shared__ u16 Ws[128*KP];

    const int t  = threadIdx.x;
    const int r0 = blockIdx.x * 128;
    const float4* xsrc = (const float4*)(x + (size_t)r0*DD);

    // stage X tile (fp32 -> bf16)
    #pragma unroll
    for (int it = 0; it < 8; ++it) {
        int i = t + 256*it;             // 2048 chunks of 8
        int e = i >> 4, c8 = i & 15;
        st8(&Xs[e*KP + c8*8], xsrc[2*i], xsrc[2*i + 1]);
    }
    // stage W for wsel=0
    #pragma unroll
    for (int it = 0; it < 8; ++it) {
        int i = t + 256*it;
        int e = i >> 4, c8 = i & 15;
        st8(&Ws[e*KP + c8*8], ((const float4*)Wq)[2*i], ((const float4*)Wq)[2*i + 1]);
    }
    __syncthreads();

    const int w   = t >> 6;
    const int l31 = t & 31;
    const int q2  = (t >> 5) & 1;

    // A-fragments: this wave's 32-row band, in registers for all 3 GEMMs
    s8v af[8];
    #pragma unroll
    for (int s = 0; s < 8; ++s)
        af[s] = ld8(&Xs[(w*32 + l31)*KP + s*16 + q2*8]);

    #pragma unroll
    for (int wsel = 0; wsel < 3; ++wsel) {
        const float* Bi = (wsel == 0) ? Bq : (wsel == 1) ? Bk : Bv;
        u16*         Ot = (wsel == 0) ? g_Q : (wsel == 1) ? g_K : g_V;

        vf16 acc[4];
        #pragma unroll
        for (int et = 0; et < 4; ++et)
            #pragma unroll
            for (int i = 0; i < 16; ++i) acc[et][i] = 0.f;

        #pragma unroll
        for (int s = 0; s < 8; ++s) {
            #pragma unroll
            for (int et = 0; et < 4; ++et) {
                s8v bf = ld8(&Ws[(et*32 + l31)*KP + s*16 + q2*8]);
                acc[et] = __builtin_amdgcn_mfma_f32_32x32x16_bf16(af[s], bf, acc[et], 0, 0, 0);
            }
        }

        float bb[4];
        #pragma unroll
        for (int et = 0; et < 4; ++et) bb[et] = Bi[et*32 + l31];

        #pragma unroll
        for (int r = 0; r < 16; ++r) {
            int rl = (r & 3) + 8*(r >> 2) + 4*q2;
            int rg = r0 + w*32 + rl;
            int b = rg >> 15, rem = rg & 32767;   // (b,t,n) -> (b,n,t)
            int tt = rem >> 4, n = rem & 15;
            size_t orow = (size_t)((b*NN + n)*TT + tt) * DD;
            #pragma unroll
            for (int et = 0; et < 4; ++et)
                Ot[orow + et*32 + l31] = f2bf(acc[et][r] + bb[et]);
        }

        if (wsel < 2) {
            const float* Wn = (wsel == 0) ? Wk : Wv;
            __syncthreads();             // everyone done reading Ws
            #pragma unroll
            for (int it = 0; it < 8; ++it) {
                int i = t + 256*it;
                int e = i >> 4, c8 = i & 15;
                st8(&Ws[e*KP + c8*8], ((const float4*)Wn)[2*i], ((const float4*)Wn)[2*i + 1]);
            }
            __syncthreads();
        }
    }
}

// ---------------------------------------------------------------------------
// Output projection: bf16 att rows (b,n,t) in g_Q -> fp32 out (b,t,n).
// ---------------------------------------------------------------------------
__global__ __launch_bounds__(256)
void out_proj_kernel(const float* __restrict__ W, const float* __restrict__ Bi,
                     float* __restrict__ out)
{
    __shared__ u16 Ws[128*KP];

    const int t  = threadIdx.x;
    const int r0 = blockIdx.x * 128;

    #pragma unroll
    for (int it = 0; it < 8; ++it) {
        int i = t + 256*it;
        int e = i >> 4, c8 = i & 15;
        st8(&Ws[e*KP + c8*8], ((const float4*)W)[2*i], ((const float4*)W)[2*i + 1]);
    }

    const int w   = t >> 6;
    const int l31 = t & 31;
    const int q2  = (t >> 5) & 1;

    s8v af[8];
    {
        const u16* src = g_Q + (size_t)(r0 + w*32 + l31)*DD;
        #pragma unroll
        for (int s = 0; s < 8; ++s)
            af[s] = *(const s8v*)&src[s*16 + q2*8];
    }
    __syncthreads();

    vf16 acc[4];
    #pragma unroll
    for (int et = 0; et < 4; ++et)
        #pragma unroll
        for (int i = 0; i < 16; ++i) acc[et][i] = 0.f;

    #pragma unroll
    for (int s = 0; s < 8; ++s) {
        #pragma unroll
        for (int et = 0; et < 4; ++et) {
            s8v bf = ld8(&Ws[(et*32 + l31)*KP + s*16 + q2*8]);
            acc[et] = __builtin_amdgcn_mfma_f32_32x32x16_bf16(af[s], bf, acc[et], 0, 0, 0);
        }
    }

    float bb[4];
    #pragma unroll
    for (int et = 0; et < 4; ++et) bb[et] = Bi[et*32 + l31];

    #pragma unroll
    for (int r = 0; r < 16; ++r) {
        int rl = (r & 3) + 8*(r >> 2) + 4*q2;
        int rg = r0 + w*32 + rl;
        int b = rg >> 15, rem = rg & 32767;   // (b,n,t) -> (b,t,n)
        int n = rem >> 11, tt = rem & 2047;
        size_t orow = (size_t)((b*TT + tt)*NN + n) * DD;
        #pragma unroll
        for (int et = 0; et < 4; ++et)
            out[orow + et*32 + l31] = acc[et][r] + bb[et];
    }
}

// ---------------------------------------------------------------------------
// V transpose (unchanged): g_V (b,n,t,d) -> g_VT (b,n,d,t).
// ---------------------------------------------------------------------------
__global__ __launch_bounds__(256)
void vtrans_kernel()
{
    const int t   = threadIdx.x;
    const int blk = blockIdx.x;
    const int pl  = blk >> 7;
    const int seg = blk & 127;
    const size_t plane = (size_t)pl * PLANE;
    const int w = t >> 6, lane = t & 63;
    const int d   = (w & 1)*64 + lane;
    const int tt0 = seg*16 + (w >> 1)*8;

    const u16* src = g_V + plane + (size_t)tt0*DD + d;
    u16 e[8];
    #pragma unroll
    for (int i = 0; i < 8; ++i) e[i] = src[(size_t)i*DD];
    uint4 pk;
    pk.x = (u32)e[0] | ((u32)e[1] << 16);
    pk.y = (u32)e[2] | ((u32)e[3] << 16);
    pk.z = (u32)e[4] | ((u32)e[5] << 16);
    pk.w = (u32)e[6] | ((u32)e[7] << 16);
    *(uint4*)&g_VT[plane + (size_t)d*TT + tt0] = pk;
}

// ---------------------------------------------------------------------------
// MFMA flash attention with register double-buffer prefetch.
// Block = (bn, q-tile 128) = 4 waves x 32-q bands; K-tile 64.
// Conflict-free LDS: Ks pitch 132, Vt pitch 68 (b64 access, 2-way = free).
// Softmax in exp2 domain. O overwrites own g_Q rows.
// ---------------------------------------------------------------------------
__global__ __launch_bounds__(256, 2)
void attn_kernel()
{
    __shared__ u16 Ks[64*KP];
    __shared__ u16 Vt[128*VP];

    const int t   = threadIdx.x;
    const int grp = blockIdx.x >> 5;              // 0..15
    const int bn  = blockIdx.x & 31;
    const int qt  = (grp < 8) ? (15 - grp) : (grp - 8);  // uniform-sum pairs
    const int q0  = qt * 128;
    const size_t plane = (size_t)bn * PLANE;
    const u16* Kg = g_K  + plane;
    const u16* Vg = g_VT + plane;

    const int w      = t >> 6;
    const int lane   = t & 63;
    const int lane31 = lane & 31;
    const int q2     = lane >> 5;
    const int qband  = q0 + 32*w;
    const int qrow   = qband + lane31;

    s8v qf[8];
    {
        const u16* Qg = g_Q + plane + (size_t)qrow * DD;
        #pragma unroll
        for (int s = 0; s < 8; ++s)
            qf[s] = *(const s8v*)&Qg[s*16 + q2*8];
    }

    vf16 accO[4];
    #pragma unroll
    for (int dt = 0; dt < 4; ++dt)
        #pragma unroll
        for (int i = 0; i < 16; ++i) accO[dt][i] = 0.f;

    float mrow = -INFINITY, lrow = 0.f;
    // scale/sqrt(D) folded with log2(e): softmax runs in exp2 domain
    const float sc2 = 0.08838834764831845f * 1.4426950408889634f;

    const int nkt = 2*qt + 2;

    // prefetch tile 0 into registers
    uint4 pk[4], pv[4];
    #pragma unroll
    for (int c = 0; c < 4; ++c) {
        int j = t + 256*c;
        int kr = j >> 4, kc = j & 15;
        pk[c] = *(const uint4*)&Kg[kr*DD + kc*8];
        int vr = j >> 3, vc = j & 7;
        pv[c] = *(const uint4*)&Vg[(size_t)vr*TT + vc*8];
    }

    for (int kt = 0; kt < nkt; ++kt) {
        const int k0 = kt*64;
        __syncthreads();                          // prev iter done with LDS
        // write prefetched tile to LDS (aligned b64 stores)
        #pragma unroll
        for (int c = 0; c < 4; ++c) {
            int j = t + 256*c;
            int kr = j >> 4, kc = j & 15;
            uint2 a, b;
            a.x = pk[c].x; a.y = pk[c].y; b.x = pk[c].z; b.y = pk[c].w;
            *(uint2*)&Ks[kr*KP + kc*8]     = a;
            *(uint2*)&Ks[kr*KP + kc*8 + 4] = b;
            int vr = j >> 3, vc = j & 7;
            a.x = pv[c].x; a.y = pv[c].y; b.x = pv[c].z; b.y = pv[c].w;
            *(uint2*)&Vt[vr*VP + vc*8]     = a;
            *(uint2*)&Vt[vr*VP + vc*8 + 4] = b;
        }
        __syncthreads();

        // issue next tile's global loads now; latency hides behind compute
        if (kt + 1 < nkt) {
            const u16* Kg2 = Kg + (size_t)(k0 + 64)*DD;
            const u16* Vg2 = Vg + (k0 + 64);
            #pragma unroll
            for (int c = 0; c < 4; ++c) {
                int j = t + 256*c;
                int kr = j >> 4, kc = j & 15;
                pk[c] = *(const uint4*)&Kg2[kr*DD + kc*8];
                int vr = j >> 3, vc = j & 7;
                pv[c] = *(const uint4*)&Vg2[(size_t)vr*TT + vc*8];
            }
        }

        if (k0 > qband + 31) continue;            // fully masked for this wave

        // ---- S^T = K · Q^T ----
        vf16 accS[2];
        #pragma unroll
        for (int kk = 0; kk < 2; ++kk)
            #pragma unroll
            for (int i = 0; i < 16; ++i) accS[kk][i] = 0.f;
        #pragma unroll
        for (int s = 0; s < 8; ++s) {
            #pragma unroll
            for (int kk = 0; kk < 2; ++kk) {
                s8v a = ld8(&Ks[(kk*32 + lane31)*KP + s*16 + q2*8]);
                accS[kk] = __builtin_amdgcn_mfma_f32_32x32x16_bf16(a, qf[s], accS[kk], 0, 0, 0);
            }
        }

        // ---- scale (exp2 domain) + causal mask ----
        float p[2][16];
        const bool tail = (k0 + 63 > qband);
        #pragma unroll
        for (int kk = 0; kk < 2; ++kk)
            #pragma unroll
            for (int r = 0; r < 16; ++r) {
                float sv = accS[kk][r] * sc2;
                if (tail) {
                    int keyg = k0 + kk*32 + (r & 3) + 8*(r >> 2) + 4*q2;
                    if (keyg > qrow) sv = -INFINITY;
                }
                p[kk][r] = sv;
            }

        // ---- online softmax (per-lane scalar m/l, one q-col) ----
        float vmax = -INFINITY;
        #pragma unroll
        for (int kk = 0; kk < 2; ++kk)
            #pragma unroll
            for (int r = 0; r < 16; ++r) vmax = fmaxf(vmax, p[kk][r]);
        vmax = fmaxf(vmax, __shfl_xor(vmax, 32));
        float mold = mrow;
        float mnew = fmaxf(mold, vmax);
        float alpha = __builtin_amdgcn_exp2f(mold - mnew);
        mrow = mnew;
        float ls = 0.f;
        #pragma unroll
        for (int kk = 0; kk < 2; ++kk)
            #pragma unroll
            for (int r = 0; r < 16; ++r) {
                float e = __builtin_amdgcn_exp2f(p[kk][r] - mnew);
                p[kk][r] = e;
                ls += e;
            }
        ls += __shfl_xor(ls, 32);
        lrow = lrow*alpha + ls;

        if (__any(mnew > mold)) {
            float ar[16];
            #pragma unroll
            for (int r = 0; r < 16; ++r)
                ar[r] = __shfl(alpha, (r & 3) + 8*(r >> 2) + 4*q2);
            #pragma unroll
            for (int dt = 0; dt < 4; ++dt)
                #pragma unroll
                for (int r = 0; r < 16; ++r) accO[dt][r] *= ar[r];
        }

        // ---- pack P (bf16 trunc) as PV A-fragments ----
        s8v pf[4];
        #pragma unroll
        for (int tau = 0; tau < 4; ++tau) {
            int kk = tau >> 1, rb = (tau & 1)*8;
            s8v v;
            #pragma unroll
            for (int j = 0; j < 8; ++j)
                v[j] = (short)(__float_as_uint(p[kk][rb + j]) >> 16);
            pf[tau] = v;
        }

        // ---- O += P · V ----
        #pragma unroll
        for (int dt = 0; dt < 4; ++dt) {
            const u16* vp = &Vt[(dt*32 + lane31)*VP];
            #pragma unroll
            for (int tau = 0; tau < 4; ++tau) {
                const u16* q = vp + 16*tau + 4*q2;
                short4 lo = *(const short4*)q;
                short4 hi = *(const short4*)(q + 8);
                s8v bvv = {lo.x, lo.y, lo.z, lo.w, hi.x, hi.y, hi.z, hi.w};
                accO[dt] = __builtin_amdgcn_mfma_f32_32x32x16_bf16(pf[tau], bvv, accO[dt], 0, 0, 0);
            }
        }
    }

    // ---- epilogue: normalize, write bf16 O over own g_Q rows ----
    float inv = 1.0f / lrow;
    #pragma unroll
    for (int r = 0; r < 16; ++r) {
        int rl = (r & 3) + 8*(r >> 2) + 4*q2;
        float ir = __shfl(inv, rl);
        u16* op = g_Q + plane + (size_t)(qband + rl)*DD;
        #pragma unroll
        for (int dt = 0; dt < 4; ++dt)
            op[dt*32 + lane31] = f2bf(accO[dt][r] * ir);
    }
}

extern "C" void kernel_launch(void* const* d_in, const int* in_sizes, int n_in,
                              void* d_out, int out_size, void* d_ws, size_t ws_size,
                              hipStream_t stream)
{
    const float* x  = (const float*)d_in[0];
    const float* wq = (const float*)d_in[1];
    const float* bq = (const float*)d_in[2];
    const float* wk = (const float*)d_in[3];
    const float* bk = (const float*)d_in[4];
    const float* wv = (const float*)d_in[5];
    const float* bv = (const float*)d_in[6];
    const float* wp = (const float*)d_in[7];
    const float* bp = (const float*)d_in[8];
    float* out = (float*)d_out;
    (void)d_ws; (void)ws_size;

    dim3 blk(256);
    qkv_proj_kernel<<<dim3(NROWS/128), blk, 0, stream>>>(
        x, wq, bq, wk, bk, wv, bv);
    vtrans_kernel<<<dim3(BB*NN*128), blk, 0, stream>>>();
    attn_kernel<<<dim3(BB*NN*(TT/128)), blk, 0, stream>>>();
    out_proj_kernel<<<dim3(NROWS/128), blk, 0, stream>>>(wp, bp, out);
}